// Round 1
// baseline (134.442 us; speedup 1.0000x reference)
//
#include <hip/hip_runtime.h>
#include <math.h>

#define NQ 10
#define NSTATE 1024   // 2^10

__device__ __forceinline__ float2 cmul(float2 a, float2 b) {
    return make_float2(fmaf(a.x, b.x, -a.y * b.y), fmaf(a.x, b.y, a.y * b.x));
}
__device__ __forceinline__ float2 cadd(float2 a, float2 b) {
    return make_float2(a.x + b.x, a.y + b.y);
}

// One block per batch row. 256 threads.
__global__ __launch_bounds__(256) void qse_kernel(
    const float* __restrict__ x,     // (4096,512)
    const float* __restrict__ W_in,  // (512,10)
    const float* __restrict__ b_in,  // (10)
    const float* __restrict__ qw,    // (2,10,3)
    const float* __restrict__ W1,    // (10,64)
    const float* __restrict__ b1,    // (64)
    const float* __restrict__ W2,    // (64,256)
    const float* __restrict__ b2,    // (256)
    float* __restrict__ out)         // (4096,256)
{
    const int b = blockIdx.x;
    const int t = threadIdx.x;
    const int lane = t & 63;
    const int wave = t >> 6;

    __shared__ float2 state[NSTATE];
    __shared__ float2 u0s[NQ], u1s[NQ];                       // fused (Rot_l0 * RX)|0> columns
    __shared__ float2 G00[NQ], G01[NQ], G10[NQ], G11[NQ];     // layer-1 Rot gates
    __shared__ float red[4][NQ];
    __shared__ float zsh[NQ];
    __shared__ float hsh[64];

    // ---------- angles = x[b] @ W_in + b_in ----------
    float acc[NQ];
    #pragma unroll
    for (int q = 0; q < NQ; ++q) acc[q] = 0.f;
    const float* xr = x + (size_t)b * 512;
    #pragma unroll
    for (int rep = 0; rep < 2; ++rep) {
        int j = t + rep * 256;
        float xv = xr[j];
        const float* wr = W_in + j * NQ;
        #pragma unroll
        for (int q = 0; q < NQ; ++q) acc[q] = fmaf(xv, wr[q], acc[q]);
    }
    #pragma unroll
    for (int off = 32; off > 0; off >>= 1) {
        #pragma unroll
        for (int q = 0; q < NQ; ++q) acc[q] += __shfl_down(acc[q], off);
    }
    if (lane == 0) {
        #pragma unroll
        for (int q = 0; q < NQ; ++q) red[wave][q] = acc[q];
    }
    __syncthreads();

    // ---------- per-qubit gate prep (threads 0..9) ----------
    if (t < NQ) {
        const int i = t;
        float ang = red[0][i] + red[1][i] + red[2][i] + red[3][i] + b_in[i];
        float s, c;
        sincosf(0.5f * ang, &s, &c);   // RX column 0 = (c, -i s)

        // layer-0 Rot
        {
            float phi = qw[i * 3 + 0], th = qw[i * 3 + 1], om = qw[i * 3 + 2];
            float st_, ct;  sincosf(0.5f * th, &st_, &ct);
            float spo, cpo; sincosf(0.5f * (phi + om), &spo, &cpo);
            float spm, cpm; sincosf(0.5f * (phi - om), &spm, &cpm);
            // R = [[epo*ct, -conj(epm)*st],[epm*st, conj(epo)*ct]], epo=(cpo,-spo), epm=(cpm,-spm)
            float2 R00 = make_float2(cpo * ct, -spo * ct);
            float2 R01 = make_float2(-cpm * st_, -spm * st_);
            float2 R10 = make_float2(cpm * st_, -spm * st_);
            float2 R11 = make_float2(cpo * ct, spo * ct);
            // U|0> = R * (c, -i s)^T ;  cmul(z, (0,-s)) = (s*z.y, -s*z.x)
            u0s[i] = make_float2(fmaf(R00.x, c, s * R01.y), fmaf(R00.y, c, -s * R01.x));
            u1s[i] = make_float2(fmaf(R10.x, c, s * R11.y), fmaf(R10.y, c, -s * R11.x));
        }
        // layer-1 Rot
        {
            float phi = qw[30 + i * 3 + 0], th = qw[30 + i * 3 + 1], om = qw[30 + i * 3 + 2];
            float st_, ct;  sincosf(0.5f * th, &st_, &ct);
            float spo, cpo; sincosf(0.5f * (phi + om), &spo, &cpo);
            float spm, cpm; sincosf(0.5f * (phi - om), &spm, &cpm);
            G00[i] = make_float2(cpo * ct, -spo * ct);
            G01[i] = make_float2(-cpm * st_, -spm * st_);
            G10[i] = make_float2(cpm * st_, -spm * st_);
            G11[i] = make_float2(cpo * ct, spo * ct);
        }
    }
    __syncthreads();

    // ---------- product state build, CNOT ring r=1 fused via index permutation ----------
    // After all layer-0 1q gates the state is a product: amp[m] = prod_i u_{bit_i(m)}[i].
    // After the CNOT ring: amp'[k] = amp[g1(k)], g1 = f_0∘f_1∘...∘f_9 applied as
    // src=k; for i=9..0: if ctrl bit(i) set, flip target bit((i+1)%10).
    #pragma unroll
    for (int j = 0; j < 4; ++j) {
        int k = t * 4 + j;
        int src = k;
        #pragma unroll
        for (int i = NQ - 1; i >= 0; --i) {
            int tq = (i + 1) % NQ;
            if ((src >> (NQ - 1 - i)) & 1) src ^= 1 << (NQ - 1 - tq);
        }
        float2 amp = make_float2(1.f, 0.f);
        #pragma unroll
        for (int i = 0; i < NQ; ++i) {
            float2 g = ((src >> (NQ - 1 - i)) & 1) ? u1s[i] : u0s[i];
            amp = cmul(amp, g);
        }
        state[k] = amp;
    }

    // ---------- layer-1 Rot gates on entangled state (pairwise in LDS) ----------
    #pragma unroll
    for (int w = 0; w < NQ; ++w) {
        __syncthreads();
        const int p = NQ - 1 - w;
        const int m = 1 << p;
        const float2 g00 = G00[w], g01 = G01[w], g10 = G10[w], g11 = G11[w];
        #pragma unroll
        for (int rep = 0; rep < 2; ++rep) {
            int pr = t + rep * 256;                       // 512 pairs
            int k0 = ((pr >> p) << (p + 1)) | (pr & (m - 1));
            int k1 = k0 | m;
            float2 a0 = state[k0], a1 = state[k1];
            state[k0] = cadd(cmul(g00, a0), cmul(g01, a1));
            state[k1] = cadd(cmul(g10, a0), cmul(g11, a1));
        }
    }
    __syncthreads();

    // ---------- readout: CNOT ring r=2 fused; z_q = sum_k prob[k]*(1-2*bit_q(k)) ----------
    float zp[NQ];
    #pragma unroll
    for (int q = 0; q < NQ; ++q) zp[q] = 0.f;
    #pragma unroll
    for (int j = 0; j < 4; ++j) {
        int k = t * 4 + j;
        int src = k;
        #pragma unroll
        for (int i = NQ - 1; i >= 0; --i) {
            int tq = (i + 2) % NQ;
            if ((src >> (NQ - 1 - i)) & 1) src ^= 1 << (NQ - 1 - tq);
        }
        float2 a = state[src];
        float pr = fmaf(a.x, a.x, a.y * a.y);
        #pragma unroll
        for (int q = 0; q < NQ; ++q)
            zp[q] += ((k >> (NQ - 1 - q)) & 1) ? -pr : pr;
    }
    #pragma unroll
    for (int off = 32; off > 0; off >>= 1) {
        #pragma unroll
        for (int q = 0; q < NQ; ++q) zp[q] += __shfl_down(zp[q], off);
    }
    __syncthreads();   // red[] reuse: ensure all prior reads done
    if (lane == 0) {
        #pragma unroll
        for (int q = 0; q < NQ; ++q) red[wave][q] = zp[q];
    }
    __syncthreads();
    if (t < NQ) zsh[t] = red[0][t] + red[1][t] + red[2][t] + red[3][t];
    __syncthreads();

    // ---------- h = relu(z @ W1 + b1) ----------
    if (t < 64) {
        float a = b1[t];
        #pragma unroll
        for (int i = 0; i < NQ; ++i) a = fmaf(zsh[i], W1[i * 64 + t], a);
        hsh[t] = fmaxf(a, 0.f);
    }
    __syncthreads();

    // ---------- out = tanh(h @ W2 + b2) ----------
    {
        float a = b2[t];
        #pragma unroll
        for (int j = 0; j < 64; ++j) a = fmaf(hsh[j], W2[j * 256 + t], a);
        out[(size_t)b * 256 + t] = tanhf(a);
    }
}

extern "C" void kernel_launch(void* const* d_in, const int* in_sizes, int n_in,
                              void* d_out, int out_size, void* d_ws, size_t ws_size,
                              hipStream_t stream) {
    const float* x    = (const float*)d_in[0];
    const float* W_in = (const float*)d_in[1];
    const float* b_in = (const float*)d_in[2];
    const float* qw   = (const float*)d_in[3];
    const float* W1   = (const float*)d_in[4];
    const float* b1   = (const float*)d_in[5];
    const float* W2   = (const float*)d_in[6];
    const float* b2   = (const float*)d_in[7];
    float* out = (float*)d_out;

    qse_kernel<<<4096, 256, 0, stream>>>(x, W_in, b_in, qw, W1, b1, W2, b2, out);
}

// Round 2
// 105.113 us; speedup vs baseline: 1.2790x; 1.2790x over previous
//
#include <hip/hip_runtime.h>
#include <math.h>

#define NQ 10
#define RPB 8          // rows per block
#define NTERMS 882

// ---------------------------------------------------------------------------
// Setup kernel: build the 882-term Pauli table from qweights (layer-1 part).
// Heisenberg picture: Z_q -> (ring2 conj) Z-string -> (Rot conj) sum of
// {X,Y,Z}-strings -> (ring1 conj, symplectic) final Pauli strings + sign.
// Term j: packed pair-nibbles (5 x 4 bits, code = x | z<<1 per site) + coef.
// ---------------------------------------------------------------------------
__global__ __launch_bounds__(1024) void qse_setup(const float* __restrict__ qw,
                                                  uint2* __restrict__ terms) {
    __shared__ float abc[NQ][3];
    const int t = threadIdx.x;
    if (t < NQ) {
        float phi = qw[30 + t * 3 + 0], th = qw[30 + t * 3 + 1], om = qw[30 + t * 3 + 2];
        float st_, ct;  sincosf(0.5f * th, &st_, &ct);
        float spo, cpo; sincosf(0.5f * (phi + om), &spo, &cpo);
        float spm, cpm; sincosf(0.5f * (phi - om), &spm, &cpm);
        float2 G00 = make_float2(cpo * ct, -spo * ct);
        float2 G01 = make_float2(-cpm * st_, -spm * st_);
        float2 G10 = make_float2(cpm * st_, -spm * st_);
        float2 G11 = make_float2(cpo * ct, spo * ct);
        // A = G† Z G ; A01 = conj(G00)G01 - conj(G10)G11
        float re = G00.x * G01.x + G00.y * G01.y - (G10.x * G11.x + G10.y * G11.y);
        float im = G00.x * G01.y - G00.y * G01.x - (G10.x * G11.y - G10.y * G11.x);
        float A00 = G00.x * G00.x + G00.y * G00.y - (G10.x * G10.x + G10.y * G10.y);
        float A11 = G01.x * G01.x + G01.y * G01.y - (G11.x * G11.x + G11.y * G11.y);
        abc[t][0] = re;                 // X coeff
        abc[t][1] = -im;                // Y coeff
        abc[t][2] = 0.5f * (A00 - A11); // Z coeff
    }
    __syncthreads();
    if (t >= NTERMS) return;

    // locate q + Z-string S_q (ring-2 conjugation: pure toggles)
    int base = 0, smask = 0;
    for (int qq = 0; qq < NQ; ++qq) {
        int m = 1 << qq;
        for (int i = NQ - 1; i >= 0; --i) {
            int tt = (i + 2) % NQ;
            if ((m >> tt) & 1) m ^= 1 << i;
        }
        int L = __popc(m);
        int cnt = 1;
        for (int k = 0; k < L; ++k) cnt *= 3;
        if (t < base + cnt) { smask = m; break; }
        base += cnt;
    }
    int rem = t - base;

    // expand: digit 0->X, 1->Y, 2->Z on each site of S_q
    unsigned xm = 0, zm = 0;
    float coef = 1.f;
    for (int i = 0; i < NQ; ++i) {
        if ((smask >> i) & 1) {
            int d = rem % 3; rem /= 3;
            coef *= abc[i][d];
            if (d == 0)      { xm |= 1u << i; }
            else if (d == 1) { xm |= 1u << i; zm |= 1u << i; }
            else             { zm |= 1u << i; }
        }
    }
    // ring-1 conjugation (CNOT(i,(i+1)%10), conjugate by i=9 first)
    unsigned s = 0;
    for (int i = NQ - 1; i >= 0; --i) {
        int c = i, tt = (i + 1) % NQ;
        unsigned xc = (xm >> c) & 1u, zt = (zm >> tt) & 1u;
        unsigned xt = (xm >> tt) & 1u, zc = (zm >> c) & 1u;
        s ^= xc & zt & (xt ^ zc ^ 1u);
        xm ^= xc << tt;
        zm ^= zt << c;
    }
    if (s) coef = -coef;

    unsigned nib = 0;
    for (int p = 0; p < 5; ++p) {
        unsigned c0 = ((xm >> (2 * p)) & 1u) | (((zm >> (2 * p)) & 1u) << 1);
        unsigned c1 = ((xm >> (2 * p + 1)) & 1u) | (((zm >> (2 * p + 1)) & 1u) << 1);
        nib |= (c0 | (c1 << 2)) << (4 * p);
    }
    terms[t] = make_uint2(nib, __float_as_uint(coef));
}

// ---------------------------------------------------------------------------
// Main kernel: 8 rows per block, 256 threads, 512 blocks.
// ---------------------------------------------------------------------------
__global__ __launch_bounds__(256) void qse_main(
    const float* __restrict__ x,     // (4096,512)
    const float* __restrict__ W_in,  // (512,10)
    const float* __restrict__ b_in,  // (10)
    const float* __restrict__ qw,    // (2,10,3)
    const float* __restrict__ W1,    // (10,64)
    const float* __restrict__ b1,    // (64)
    const float* __restrict__ W2,    // (64,256)
    const float* __restrict__ b2,    // (256)
    const uint2* __restrict__ terms, // (882)
    float* __restrict__ out)         // (4096,256)
{
    __shared__ float ang[RPB][NQ];
    __shared__ float E1[RPB][NQ][4];     // per-site {1, <X>, <Z>, <Y>}  (code = x|z<<1)
    __shared__ float E2s[RPB][5][16];    // pair products
    __shared__ float zsh[RPB][NQ];
    __shared__ float hsh[RPB][64];

    const int t = threadIdx.x;
    const int row0 = blockIdx.x * RPB;

    // ---- p1: angles = x @ W_in (32 lanes per row) ----
    {
        const int r = t >> 5, c0 = t & 31;
        float acc[NQ];
        #pragma unroll
        for (int q = 0; q < NQ; ++q) acc[q] = 0.f;
        const float* xr = x + (size_t)(row0 + r) * 512;
        for (int k = 0; k < 16; ++k) {
            int j = c0 + 32 * k;
            float xv = xr[j];
            const float* w = W_in + j * NQ;
            #pragma unroll
            for (int q = 0; q < NQ; ++q) acc[q] = fmaf(xv, w[q], acc[q]);
        }
        #pragma unroll
        for (int off = 16; off > 0; off >>= 1) {
            #pragma unroll
            for (int q = 0; q < NQ; ++q) acc[q] += __shfl_xor(acc[q], off);
        }
        if (c0 == 0) {
            #pragma unroll
            for (int q = 0; q < NQ; ++q) ang[r][q] = acc[q];
        }
    }
    if (t < RPB * NQ) zsh[t / NQ][t % NQ] = 0.f;
    __syncthreads();

    // ---- p2: per-(row,qubit) Bloch expectations of u = Rot0 * RX |0> ----
    if (t < RPB * NQ) {
        const int rr = t / NQ, i = t % NQ;
        float a = ang[rr][i] + b_in[i];
        float s, c; sincosf(0.5f * a, &s, &c);
        float phi = qw[i * 3 + 0], th = qw[i * 3 + 1], om = qw[i * 3 + 2];
        float st_, ct;  sincosf(0.5f * th, &st_, &ct);
        float spo, cpo; sincosf(0.5f * (phi + om), &spo, &cpo);
        float spm, cpm; sincosf(0.5f * (phi - om), &spm, &cpm);
        float2 R00 = make_float2(cpo * ct, -spo * ct);
        float2 R01 = make_float2(-cpm * st_, -spm * st_);
        float2 R10 = make_float2(cpm * st_, -spm * st_);
        float2 R11 = make_float2(cpo * ct, spo * ct);
        float2 u0 = make_float2(fmaf(R00.x, c, s * R01.y), fmaf(R00.y, c, -s * R01.x));
        float2 u1 = make_float2(fmaf(R10.x, c, s * R11.y), fmaf(R10.y, c, -s * R11.x));
        float ex = 2.f * (u0.x * u1.x + u0.y * u1.y);
        float ey = 2.f * (u0.x * u1.y - u0.y * u1.x);
        float ez = u0.x * u0.x + u0.y * u0.y - u1.x * u1.x - u1.y * u1.y;
        E1[rr][i][0] = 1.f; E1[rr][i][1] = ex; E1[rr][i][2] = ez; E1[rr][i][3] = ey;
    }
    __syncthreads();
    if (t < RPB * 5) {
        const int rr = t / 5, p = t % 5;
        #pragma unroll
        for (int c1 = 0; c1 < 4; ++c1)
            #pragma unroll
            for (int c0 = 0; c0 < 4; ++c0)
                E2s[rr][p][c0 | (c1 << 2)] = E1[rr][2 * p][c0] * E1[rr][2 * p + 1][c1];
    }
    __syncthreads();

    // ---- p3: contract 882 terms (threads partitioned by output q) ----
    {
        int q, l, nqt, off, cnt;
        if      (t < 24)  { q = 0; l = t;       nqt = 24; off = 0;   cnt = 81;  }
        else if (t < 48)  { q = 1; l = t - 24;  nqt = 24; off = 81;  cnt = 81;  }
        else if (t < 51)  { q = 2; l = t - 48;  nqt = 3;  off = 162; cnt = 9;   }
        else if (t < 54)  { q = 3; l = t - 51;  nqt = 3;  off = 171; cnt = 9;   }
        else if (t < 62)  { q = 4; l = t - 54;  nqt = 8;  off = 180; cnt = 27;  }
        else if (t < 70)  { q = 5; l = t - 62;  nqt = 8;  off = 207; cnt = 27;  }
        else if (t < 94)  { q = 6; l = t - 70;  nqt = 24; off = 234; cnt = 81;  }
        else if (t < 118) { q = 7; l = t - 94;  nqt = 24; off = 315; cnt = 81;  }
        else if (t < 187) { q = 8; l = t - 118; nqt = 69; off = 396; cnt = 243; }
        else              { q = 9; l = t - 187; nqt = 69; off = 639; cnt = 243; }

        float accR[RPB];
        #pragma unroll
        for (int rr = 0; rr < RPB; ++rr) accR[rr] = 0.f;

        #pragma unroll
        for (int jj = 0; jj < 4; ++jj) {
            int j = off + l + jj * nqt;
            uint2 tm = make_uint2(0u, 0u);
            if (j < off + cnt) tm = terms[j];
            const float coef = __uint_as_float(tm.y);
            const unsigned nib = tm.x;
            #pragma unroll
            for (int rr = 0; rr < RPB; ++rr) {
                float pr = coef;
                #pragma unroll
                for (int p = 0; p < 5; ++p)
                    pr *= E2s[rr][p][(nib >> (4 * p)) & 15u];
                accR[rr] += pr;
            }
        }
        #pragma unroll
        for (int rr = 0; rr < RPB; ++rr) atomicAdd(&zsh[rr][q], accR[rr]);
    }
    __syncthreads();

    // ---- p4: h = relu(z @ W1 + b1) ----
    #pragma unroll
    for (int job = t; job < RPB * 64; job += 256) {
        const int rr = job >> 6, c = job & 63;
        float a = b1[c];
        #pragma unroll
        for (int i = 0; i < NQ; ++i) a = fmaf(zsh[rr][i], W1[i * 64 + c], a);
        hsh[rr][c] = fmaxf(a, 0.f);
    }
    __syncthreads();

    // ---- p5: out = tanh(h @ W2 + b2), thread owns column t for 8 rows ----
    {
        float oacc[RPB];
        #pragma unroll
        for (int rr = 0; rr < RPB; ++rr) oacc[rr] = b2[t];
        for (int j4 = 0; j4 < 16; ++j4) {
            float4 hv[RPB];
            #pragma unroll
            for (int rr = 0; rr < RPB; ++rr) hv[rr] = *(const float4*)&hsh[rr][4 * j4];
            const float w0 = W2[(4 * j4 + 0) * 256 + t];
            const float w1 = W2[(4 * j4 + 1) * 256 + t];
            const float w2 = W2[(4 * j4 + 2) * 256 + t];
            const float w3 = W2[(4 * j4 + 3) * 256 + t];
            #pragma unroll
            for (int rr = 0; rr < RPB; ++rr) {
                oacc[rr] = fmaf(hv[rr].x, w0, oacc[rr]);
                oacc[rr] = fmaf(hv[rr].y, w1, oacc[rr]);
                oacc[rr] = fmaf(hv[rr].z, w2, oacc[rr]);
                oacc[rr] = fmaf(hv[rr].w, w3, oacc[rr]);
            }
        }
        #pragma unroll
        for (int rr = 0; rr < RPB; ++rr)
            out[(size_t)(row0 + rr) * 256 + t] = tanhf(oacc[rr]);
    }
}

extern "C" void kernel_launch(void* const* d_in, const int* in_sizes, int n_in,
                              void* d_out, int out_size, void* d_ws, size_t ws_size,
                              hipStream_t stream) {
    const float* x    = (const float*)d_in[0];
    const float* W_in = (const float*)d_in[1];
    const float* b_in = (const float*)d_in[2];
    const float* qw   = (const float*)d_in[3];
    const float* W1   = (const float*)d_in[4];
    const float* b1   = (const float*)d_in[5];
    const float* W2   = (const float*)d_in[6];
    const float* b2   = (const float*)d_in[7];
    float* out = (float*)d_out;
    uint2* terms = (uint2*)d_ws;   // 882 * 8B = 7056 B

    qse_setup<<<1, 1024, 0, stream>>>(qw, terms);
    qse_main<<<4096 / RPB, 256, 0, stream>>>(x, W_in, b_in, qw, W1, b1, W2, b2,
                                             (const uint2*)terms, out);
}